// Round 14
// baseline (225.173 us; speedup 1.0000x reference)
//
#include <hip/hip_runtime.h>

// grica power-whitening encoder, MI355X.
//   K1 k_pass    : fused MFMA GEMM y = x@Wfc^T AND C0sum += y^T y.
//                  512-thread blocks, LDS-pinned 2 blocks/CU; launch_bounds
//                  (512,2) -> 256-VGPR cap gives the scheduler headroom to
//                  software-pipeline x-loads across ks iterations (unroll 4).
//                  B = split-bf16 Wfc staged once per block in LDS (stride 264
//                  shorts, bank-even). y-GEMM is 2-product trunc(x)*(Wh+Wl).
//                  y stored as bf16 (RNE) in the UPPER 128B of each row's
//                  256B out-slot (halves y write+read traffic; cov keeps full
//                  f32 accY precision in-register). Per tile: y-GEMM -> y bf16
//                  store -> 30 cov MFMAs (3-product) into persistent accC[10].
//                  End: block LDS reduction -> one atomicAdd set per block.
//   K2 k_whiten_ns : W = C^(-1/2), MFMA split-bf16 NS, 512 thr, dual-step.
//   K3 k_yw      : out = y_bf16 @ W in place. Row-exclusive per wave: reads
//                  its rows' bf16 (upper half of slot) then overwrites the
//                  same rows' f32 -- race-free by within-wave program order.
//   C0sum zeroed via hipMemsetAsync (graph-capture-safe).

#define NS_ITERS 10
#define BSTRIDE 264      // k_pass LDS B row stride in shorts (256 + 8 pad)
#define WST 72           // whiten LDS row stride in shorts (64 + 8 pad)

typedef __attribute__((ext_vector_type(8))) short bf16x8;
typedef __attribute__((ext_vector_type(4))) float f32x4;

__device__ __forceinline__ void split8(float4 u, float4 v, bf16x8 &hi, bf16x8 &lo){
  const float f[8] = {u.x,u.y,u.z,u.w, v.x,v.y,v.z,v.w};
  #pragma unroll
  for (int i=0;i<8;i++){
    const unsigned b  = __float_as_uint(f[i]);
    const unsigned hb = b & 0xFFFF0000u;
    hi[i] = (short)(hb >> 16);
    lo[i] = (short)(__float_as_uint(f[i] - __uint_as_float(hb)) >> 16);
  }
}

// truncate 8 f32 to bf16 (top 16 bits), no lo term.
__device__ __forceinline__ bf16x8 trunc8(float4 u, float4 v){
  const float f[8] = {u.x,u.y,u.z,u.w, v.x,v.y,v.z,v.w};
  bf16x8 h;
  #pragma unroll
  for (int i=0;i<8;i++) h[i] = (short)(__float_as_uint(f[i]) >> 16);
  return h;
}

#define MFMA16(a,b,c) __builtin_amdgcn_mfma_f32_16x16x32_bf16((a),(b),(c),0,0,0)

// Fused y-GEMM + covariance. 256-row tiles (8 waves x 32 rows), grid-stride.
// (512,2): LDS pins occupancy at 2 blocks/CU anyway; VGPR cap 256 frees the
// scheduler to pipeline x-loads across unrolled ks iterations.
__global__ __launch_bounds__(512,2) void k_pass(const float* __restrict__ x,
                                                const float* __restrict__ Wfc,
                                                float* __restrict__ y,
                                                float* __restrict__ C0sum,
                                                int N, int ntiles){
  __shared__ __align__(16) unsigned short SMEM[2*64*BSTRIDE];
  unsigned short* Bh = SMEM;
  unsigned short* Bl = SMEM + 64*BSTRIDE;
  const int t  = threadIdx.x;
  const int wv = t>>6, l = t&63;
  const int lg = l>>4, lr = l&15;

  // one-time stage: split Wfc (64x256 f32, L2/L3-hot) into LDS bf16 hi/lo.
  #pragma unroll
  for (int q=0; q<4; ++q){
    const int idx = q*512 + t;              // 2048 chunks of 8 floats
    const int row = idx>>5, c8 = (idx&31)*8;
    const float4 f0 = *(const float4*)&Wfc[row*256 + c8];
    const float4 f1 = *(const float4*)&Wfc[row*256 + c8 + 4];
    bf16x8 h, lo;
    split8(f0, f1, h, lo);
    *(bf16x8*)&Bh[row*BSTRIDE + c8] = h;
    *(bf16x8*)&Bl[row*BSTRIDE + c8] = lo;
  }
  __syncthreads();

  // persistent symmetric-C accumulators: upper pairs (a<=b)
  f32x4 accC[10];
  #pragma unroll
  for (int p=0;p<10;p++) accC[p] = (f32x4){0.f,0.f,0.f,0.f};

  unsigned short* yb = (unsigned short*)y;   // bf16 y at row*128 + 64

  for (int tile = blockIdx.x; tile < ntiles; tile += gridDim.x){
    const long r0 = (long)tile*256 + 32*wv;   // wave's 32 rows

    f32x4 accY[2][4];
    #pragma unroll
    for (int rb=0;rb<2;rb++)
      #pragma unroll
      for (int cb=0;cb<4;cb++) accY[rb][cb] = (f32x4){0.f,0.f,0.f,0.f};

    #pragma unroll 4
    for (int ks=0; ks<8; ++ks){
      const int kl = 32*ks + 8*lg;                 // lane's 8 consecutive k
      bf16x8 ahi[2];
      #pragma unroll
      for (int rb=0; rb<2; ++rb){
        const long row = r0 + 16*rb + lr;          // A row = lane&15
        float4 a0, a1;
        if (row < (long)N){
          a0 = *(const float4*)&x[row*256 + kl];
          a1 = *(const float4*)&x[row*256 + kl + 4];
        } else {
          a0 = make_float4(0.f,0.f,0.f,0.f);
          a1 = make_float4(0.f,0.f,0.f,0.f);
        }
        ahi[rb] = trunc8(a0, a1);
      }
      #pragma unroll
      for (int cb=0; cb<4; ++cb){
        const bf16x8 bhi = *(const bf16x8*)&Bh[(16*cb+lr)*BSTRIDE + kl];
        const bf16x8 blo = *(const bf16x8*)&Bl[(16*cb+lr)*BSTRIDE + kl];
        #pragma unroll
        for (int rb=0; rb<2; ++rb){
          accY[rb][cb] = MFMA16(ahi[rb], bhi, accY[rb][cb]);
          accY[rb][cb] = MFMA16(ahi[rb], blo, accY[rb][cb]);
        }
      }
    }

    // y -> global bf16 (RNE), upper 128B of each row's out-slot.
    // C/D layout (m89-verified): col = lane&15, row = 4*(lane>>4)+i
    #pragma unroll
    for (int rb=0; rb<2; ++rb){
      #pragma unroll
      for (int cb=0; cb<4; ++cb){
        #pragma unroll
        for (int i=0;i<4;i++){
          const long row = r0 + 16*rb + 4*lg + i;
          if (row < (long)N){
            const unsigned b  = __float_as_uint(accY[rb][cb][i]);
            const unsigned rn = (b + 0x7FFFu + ((b>>16)&1u)) >> 16;
            yb[row*128 + 64 + 16*cb + lr] = (unsigned short)rn;
          }
        }
      }
    }

    // in-register C contribution (K=32 = this wave's rows), full 3-product.
    // k-slot j of lane (lg,lr) := local row 16*(j>>2)+4*lg+(j&3); A and B
    // fragments share the map, MFMA k-reduction is a pure sum (r2-verified).
    bf16x8 chi[4], clo[4];
    #pragma unroll
    for (int g=0; g<4; ++g){
      const float4 u = make_float4(accY[0][g][0],accY[0][g][1],accY[0][g][2],accY[0][g][3]);
      const float4 v = make_float4(accY[1][g][0],accY[1][g][1],accY[1][g][2],accY[1][g][3]);
      split8(u, v, chi[g], clo[g]);
    }
    {
      int p = 0;
      #pragma unroll
      for (int a=0; a<4; ++a){
        #pragma unroll
        for (int b=a; b<4; ++b){
          accC[p] = MFMA16(chi[a], chi[b], accC[p]);
          accC[p] = MFMA16(clo[a], chi[b], accC[p]);
          accC[p] = MFMA16(chi[a], clo[b], accC[p]);
          ++p;
        }
      }
    }
  }

  // ---- block reduction of accC (8 waves -> 1), reusing the B LDS.
  __syncthreads();                       // B no longer needed
  float* red = (float*)SMEM;             // 4*10*256 floats = 40 KB (fits 66 KB)
  if (wv < 4){
    #pragma unroll
    for (int p=0;p<10;p++)
      *(f32x4*)&red[(wv*10+p)*256 + l*4] = accC[p];
  }
  __syncthreads();
  if (wv >= 4){
    #pragma unroll
    for (int p=0;p<10;p++){
      f32x4 v = *(f32x4*)&red[((wv-4)*10+p)*256 + l*4];
      v += accC[p];
      *(f32x4*)&red[((wv-4)*10+p)*256 + l*4] = v;
    }
  }
  __syncthreads();

  // one atomicAdd set per block: 2560 upper-triangle elements.
  for (int e = t; e < 2560; e += 512){
    const int p = e>>8, li = (e>>2)&63, i = e&3;
    const float s = red[(0*10+p)*256 + li*4 + i] + red[(1*10+p)*256 + li*4 + i]
                  + red[(2*10+p)*256 + li*4 + i] + red[(3*10+p)*256 + li*4 + i];
    const int a = (p>=4) + (p>=7) + (p>=9);
    const int off = (a==0) ? 0 : (a==1) ? 4 : (a==2) ? 7 : 9;
    const int b = a + (p - off);
    const int m = 16*a + 4*(li>>4) + i;
    const int n = 16*b + (li&15);
    atomicAdd(&C0sum[m*64 + n], s);
  }
}

#define WMAXRED(s) { s=fmaxf(s,__shfl_xor(s,32)); s=fmaxf(s,__shfl_xor(s,16)); \
  s=fmaxf(s,__shfl_xor(s,8)); s=fmaxf(s,__shfl_xor(s,4)); \
  s=fmaxf(s,__shfl_xor(s,2)); s=fmaxf(s,__shfl_xor(s,1)); }

// Coupled Newton-Schulz for C^(-1/2) via MFMA split-bf16, 512 threads.
// A=C/tau (Gershgorin tau), Y=A, Z=I; T=1.5I-0.5ZY; Y<-YT; Z<-TZ; W=Z/sqrt(tau).
// Per iter: T-step (8 waves: row-block w>>1, 2 col-blocks each), barrier,
// DUAL step (waves 0-3: U=Y*T; waves 4-7: V=T*Z), barrier; rotate 5 buffers.
// C0sum is block-upper-triangular (16x16 tiles): symmetrize on load.
__global__ __launch_bounds__(512,1) void k_whiten_ns(const float* __restrict__ C0sum,
                                                     unsigned short* __restrict__ Wh2,
                                                     unsigned short* __restrict__ Wl2,
                                                     float invN){
  __shared__ __align__(16) unsigned short SM[10][64*WST]; // Y,Z,T,U,V (hi,lo each)
  __shared__ float sred[8];

  const int t = threadIdx.x;
  const int w = t>>6, l = t&63;
  const int lg = l>>4, lr = l&15;
  const int di = t>>3, djb = (t&7)*8;     // thread: row di, cols [djb, djb+8)

  // ---- load C (symmetrize), Gershgorin tau
  const bool upper = (((t&7)>>1) >= (di>>4));   // col-tile >= row-tile
  float4 cv[2];
  float psum = 0.f;
  #pragma unroll
  for (int c=0;c<2;c++){
    if (upper){
      cv[c] = *(const float4*)&C0sum[di*64 + djb + 4*c];
    } else {
      const int j0 = djb + 4*c;
      cv[c] = make_float4(C0sum[(j0+0)*64 + di], C0sum[(j0+1)*64 + di],
                          C0sum[(j0+2)*64 + di], C0sum[(j0+3)*64 + di]);
    }
    psum += fabsf(cv[c].x)+fabsf(cv[c].y)+fabsf(cv[c].z)+fabsf(cv[c].w);
  }
  psum *= invN;
  psum += __shfl_xor(psum,1);
  psum += __shfl_xor(psum,2);
  psum += __shfl_xor(psum,4);
  float m = psum;
  WMAXRED(m);
  if (l==0) sred[w] = m;
  __syncthreads();
  float tau = sred[0];
  #pragma unroll
  for (int i=1;i<8;i++) tau = fmaxf(tau, sred[i]);
  const float sA = invN/tau;

  // ---- init Y = A (split), Z = I (split)
  #pragma unroll
  for (int c=0;c<2;c++){
    const float vv[4] = {cv[c].x*sA, cv[c].y*sA, cv[c].z*sA, cv[c].w*sA};
    #pragma unroll
    for (int e=0;e<4;e++){
      const int j = djb + 4*c + e;
      const unsigned b  = __float_as_uint(vv[e]);
      const unsigned hb = b & 0xFFFF0000u;
      SM[0][di*WST + j] = (unsigned short)(hb >> 16);
      SM[1][di*WST + j] =
          (unsigned short)(__float_as_uint(vv[e] - __uint_as_float(hb)) >> 16);
      SM[2][di*WST + j] = (di==j) ? (unsigned short)0x3F80 : (unsigned short)0;
      SM[3][di*WST + j] = 0;
    }
  }
  __syncthreads();

  unsigned short *pYh=SM[0], *pYl=SM[1], *pZh=SM[2], *pZl=SM[3];
  unsigned short *pTh=SM[4], *pTl=SM[5], *pUh=SM[6], *pUl=SM[7];
  unsigned short *pVh=SM[8], *pVl=SM[9];

  // pack+store one 16x16 D tile transposed (D symmetric): val at (row,col)
  // stored at [col][row]; row = 16*rw+4*lg+i, col = 16*cb+lr.
  auto storeT = [&](unsigned short* Dh, unsigned short* Dl,
                    const f32x4& a, int rw, int cb, bool isT){
    unsigned hh[4], ll[4];
    #pragma unroll
    for (int i=0;i<4;i++){
      float v = a[i];
      if (isT) v = -0.5f*v + ((16*rw+4*lg+i == 16*cb+lr) ? 1.5f : 0.f);
      const unsigned b  = __float_as_uint(v);
      const unsigned hb = b & 0xFFFF0000u;
      hh[i] = hb >> 16;
      ll[i] = __float_as_uint(v - __uint_as_float(hb)) >> 16;
    }
    const int base = (16*cb+lr)*WST + 16*rw + 4*lg;
    *(uint2*)&Dh[base] = make_uint2(hh[0] | (hh[1]<<16), hh[2] | (hh[3]<<16));
    *(uint2*)&Dl[base] = make_uint2(ll[0] | (ll[1]<<16), ll[2] | (ll[3]<<16));
  };

  // T-step: this wave computes rows [16*rw,16*rw+16), cols 2 blocks from cb0.
  auto mm2 = [&](unsigned short* Dh, unsigned short* Dl,
                 const unsigned short* Ah, const unsigned short* Al,
                 const unsigned short* Bh, const unsigned short* Bl,
                 int rw, int cb0){
    f32x4 acc[2];
    acc[0] = (f32x4){0.f,0.f,0.f,0.f};
    acc[1] = (f32x4){0.f,0.f,0.f,0.f};
    #pragma unroll
    for (int ks=0; ks<2; ++ks){
      const int kl = 32*ks + 8*lg;
      const bf16x8 ahi = *(const bf16x8*)&Ah[(16*rw+lr)*WST + kl];
      const bf16x8 alo = *(const bf16x8*)&Al[(16*rw+lr)*WST + kl];
      #pragma unroll
      for (int cbi=0; cbi<2; ++cbi){
        const bf16x8 bhi = *(const bf16x8*)&Bh[(16*(cb0+cbi)+lr)*WST + kl];
        const bf16x8 blo = *(const bf16x8*)&Bl[(16*(cb0+cbi)+lr)*WST + kl];
        acc[cbi] = MFMA16(ahi, bhi, acc[cbi]);
        acc[cbi] = MFMA16(alo, bhi, acc[cbi]);
        acc[cbi] = MFMA16(ahi, blo, acc[cbi]);
      }
    }
    storeT(Dh, Dl, acc[0], rw, cb0+0, true);
    storeT(Dh, Dl, acc[1], rw, cb0+1, true);
  };

  // dual-step: full-width mm, this wave computes rows [16*rw,16*rw+16), 4 cbs.
  auto mm4 = [&](unsigned short* Dh, unsigned short* Dl,
                 const unsigned short* Ah, const unsigned short* Al,
                 const unsigned short* Bh, const unsigned short* Bl, int rw){
    f32x4 acc[4];
    #pragma unroll
    for (int cb=0;cb<4;cb++) acc[cb] = (f32x4){0.f,0.f,0.f,0.f};
    #pragma unroll
    for (int ks=0; ks<2; ++ks){
      const int kl = 32*ks + 8*lg;
      const bf16x8 ahi = *(const bf16x8*)&Ah[(16*rw+lr)*WST + kl];
      const bf16x8 alo = *(const bf16x8*)&Al[(16*rw+lr)*WST + kl];
      #pragma unroll
      for (int cb=0; cb<4; ++cb){
        const bf16x8 bhi = *(const bf16x8*)&Bh[(16*cb+lr)*WST + kl];
        const bf16x8 blo = *(const bf16x8*)&Bl[(16*cb+lr)*WST + kl];
        acc[cb] = MFMA16(ahi, bhi, acc[cb]);
        acc[cb] = MFMA16(alo, bhi, acc[cb]);
        acc[cb] = MFMA16(ahi, blo, acc[cb]);
      }
    }
    #pragma unroll
    for (int cb=0;cb<4;cb++) storeT(Dh, Dl, acc[cb], rw, cb, false);
  };

  #pragma unroll 1
  for (int it=0; it<NS_ITERS; ++it){
    // T = 1.5I - 0.5 Z Y : all 8 waves (row-block w>>1, col-blocks 2*(w&1)+)
    mm2(pTh,pTl, pZh,pZl, pYh,pYl, w>>1, 2*(w&1));
    __syncthreads();
    // dual: waves 0-3: U = Y*T (new Y, skip on last); waves 4-7: V = T*Z (new Z)
    if (w < 4){
      if (it < NS_ITERS-1) mm4(pUh,pUl, pYh,pYl, pTh,pTl, w);
    } else {
      mm4(pVh,pVl, pTh,pTl, pZh,pZl, w-4);
    }
    __syncthreads();
    unsigned short *oYh=pYh,*oYl=pYl,*oZh=pZh,*oZl=pZl,*oTh=pTh,*oTl=pTl;
    pYh=pUh; pYl=pUl; pZh=pVh; pZl=pVl;
    pTh=oYh; pTl=oYl; pUh=oZh; pUl=oZl; pVh=oTh; pVl=oTl;
  }

  // ---- W = Z / sqrt(tau): reconstruct, scale, re-split, store global
  const float fs = rsqrtf(tau);
  #pragma unroll
  for (int c=0;c<2;c++){
    #pragma unroll
    for (int e=0;e<4;e++){
      const int j = djb + 4*c + e;
      const float zh = __uint_as_float(((unsigned)pZh[di*WST + j]) << 16);
      const float zl = __uint_as_float(((unsigned)pZl[di*WST + j]) << 16);
      const float v  = (zh + zl) * fs;
      const unsigned b  = __float_as_uint(v);
      const unsigned hb = b & 0xFFFF0000u;
      Wh2[di*64 + j] = (unsigned short)(hb >> 16);
      Wl2[di*64 + j] =
          (unsigned short)(__float_as_uint(v - __uint_as_float(hb)) >> 16);
    }
  }
}

// In-place MFMA: out[row] = y_bf16[row] @ W. y bf16 lives in the upper 128B
// of each row's 256B out-slot; W symmetric split-bf16 (16KB, L1-resident).
// Wave wv owns rows [32wv,32wv+32) exclusively (reads its rows' bf16, then
// overwrites the same rows' f32 -- within-wave program order, race-free).
__global__ __launch_bounds__(256,4) void k_yw(float* yio,
                                              const unsigned short* __restrict__ Wh2,
                                              const unsigned short* __restrict__ Wl2,
                                              int N){
  const int t  = threadIdx.x;
  const int wv = t>>6, l = t&63;
  const int lg = l>>4, lr = l&15;
  const long r0 = (long)blockIdx.x*128;
  const unsigned short* yb = (const unsigned short*)yio;

  f32x4 acc[2][4];
  #pragma unroll
  for (int rb=0;rb<2;rb++)
    #pragma unroll
    for (int cb=0;cb<4;cb++) acc[rb][cb] = (f32x4){0.f,0.f,0.f,0.f};

  #pragma unroll
  for (int ks=0; ks<2; ++ks){
    const int kl = 32*ks + 8*lg;
    bf16x8 ahi[2];
    #pragma unroll
    for (int rb=0; rb<2; ++rb){
      const long row = r0 + 32*wv + 16*rb + lr;
      if (row < (long)N)
        ahi[rb] = *(const bf16x8*)&yb[row*128 + 64 + kl];
      else
        ahi[rb] = (bf16x8){0,0,0,0,0,0,0,0};
    }
    #pragma unroll
    for (int cb=0; cb<4; ++cb){
      const bf16x8 bhi = *(const bf16x8*)&Wh2[(16*cb+lr)*64 + kl];
      const bf16x8 blo = *(const bf16x8*)&Wl2[(16*cb+lr)*64 + kl];
      #pragma unroll
      for (int rb=0; rb<2; ++rb){
        acc[rb][cb] = MFMA16(ahi[rb], bhi, acc[rb][cb]);
        acc[rb][cb] = MFMA16(ahi[rb], blo, acc[rb][cb]);
      }
    }
  }

  #pragma unroll
  for (int rb=0; rb<2; ++rb){
    #pragma unroll
    for (int cb=0; cb<4; ++cb){
      #pragma unroll
      for (int i=0;i<4;i++){
        const long row = r0 + 32*wv + 16*rb + 4*lg + i;
        if (row < (long)N) yio[row*64 + 16*cb + lr] = acc[rb][cb][i];
      }
    }
  }
}

extern "C" void kernel_launch(void* const* d_in, const int* in_sizes, int n_in,
                              void* d_out, int out_size, void* d_ws, size_t ws_size,
                              hipStream_t stream) {
  const float* x   = (const float*)d_in[0];   // [N,256]
  const float* Wfc = (const float*)d_in[1];   // [64,256]
  const float* R   = (const float*)d_in[2];   // unused: W = C^-1/2 exactly
  float* out = (float*)d_out;                 // [N,64] (holds y bf16, then out)
  char*  ws  = (char*)d_ws;
  (void)R;

  float*          C0sum = (float*)(ws + 0);               // 16 KB
  unsigned short* Wh2   = (unsigned short*)(ws + 16384);  //  8 KB (split W)
  unsigned short* Wl2   = (unsigned short*)(ws + 24576);  //  8 KB

  const int N = in_sizes[0] / 256;
  const int nt128 = (N + 127)/128;
  const int nt256 = (N + 255)/256;

  hipMemsetAsync(C0sum, 0, 16384, stream);
  k_pass     <<<512,   512, 0, stream>>>(x, Wfc, out, C0sum, N, nt256);
  k_whiten_ns<<<1,     512, 0, stream>>>(C0sum, Wh2, Wl2, 1.0f/(float)N);
  k_yw       <<<nt128, 256, 0, stream>>>(out, Wh2, Wl2, N);
}

// Round 15
// 209.261 us; speedup vs baseline: 1.0760x; 1.0760x over previous
//
#include <hip/hip_runtime.h>

// grica power-whitening encoder, MI355X.  (r13 structure = session best)
//   K1 k_pass    : fused MFMA GEMM y = x@Wfc^T AND C0sum += y^T y.
//                  512-thread blocks, (512,4), 2 blocks/CU (LDS-pinned).
//                  B = split-bf16 Wfc staged once per block in LDS (stride 264
//                  shorts, bank-even). y-GEMM is 2-product trunc(x)*(Wh+Wl).
//                  y stored as bf16 (RNE) in the UPPER 128B of each row's
//                  256B out-slot (halves y write+read traffic; cov keeps full
//                  f32 accY precision in-register). Per tile: y-GEMM -> y bf16
//                  store -> 30 cov MFMAs (3-product) into persistent accC[10].
//                  End: block LDS reduction -> one atomicAdd set per block.
//                  NOTE: scheduling attacks all neutral (r8 unroll, r11 issue
//                  width, r12 async DMA, r14 VGPR headroom) -- k_pass sits at
//                  the ~4 TB/s empirical mixed-stream ceiling for this pattern.
//   K2 k_whiten_ns : W = C^(-1/2), MFMA split-bf16 NS, 512 thr, dual-step.
//   K3 k_yw      : out = y_bf16 @ W in place, (256,6) for extra TLP.
//   C0sum zeroed via hipMemsetAsync (graph-capture-safe).

#define NS_ITERS 10
#define BSTRIDE 264      // k_pass LDS B row stride in shorts (256 + 8 pad)
#define WST 72           // whiten LDS row stride in shorts (64 + 8 pad)

typedef __attribute__((ext_vector_type(8))) short bf16x8;
typedef __attribute__((ext_vector_type(4))) float f32x4;

__device__ __forceinline__ void split8(float4 u, float4 v, bf16x8 &hi, bf16x8 &lo){
  const float f[8] = {u.x,u.y,u.z,u.w, v.x,v.y,v.z,v.w};
  #pragma unroll
  for (int i=0;i<8;i++){
    const unsigned b  = __float_as_uint(f[i]);
    const unsigned hb = b & 0xFFFF0000u;
    hi[i] = (short)(hb >> 16);
    lo[i] = (short)(__float_as_uint(f[i] - __uint_as_float(hb)) >> 16);
  }
}

// truncate 8 f32 to bf16 (top 16 bits), no lo term.
__device__ __forceinline__ bf16x8 trunc8(float4 u, float4 v){
  const float f[8] = {u.x,u.y,u.z,u.w, v.x,v.y,v.z,v.w};
  bf16x8 h;
  #pragma unroll
  for (int i=0;i<8;i++) h[i] = (short)(__float_as_uint(f[i]) >> 16);
  return h;
}

#define MFMA16(a,b,c) __builtin_amdgcn_mfma_f32_16x16x32_bf16((a),(b),(c),0,0,0)

// Fused y-GEMM + covariance. 256-row tiles (8 waves x 32 rows), grid-stride.
__global__ __launch_bounds__(512,4) void k_pass(const float* __restrict__ x,
                                                const float* __restrict__ Wfc,
                                                float* __restrict__ y,
                                                float* __restrict__ C0sum,
                                                int N, int ntiles){
  __shared__ __align__(16) unsigned short SMEM[2*64*BSTRIDE];
  unsigned short* Bh = SMEM;
  unsigned short* Bl = SMEM + 64*BSTRIDE;
  const int t  = threadIdx.x;
  const int wv = t>>6, l = t&63;
  const int lg = l>>4, lr = l&15;

  // one-time stage: split Wfc (64x256 f32, L2/L3-hot) into LDS bf16 hi/lo.
  #pragma unroll
  for (int q=0; q<4; ++q){
    const int idx = q*512 + t;              // 2048 chunks of 8 floats
    const int row = idx>>5, c8 = (idx&31)*8;
    const float4 f0 = *(const float4*)&Wfc[row*256 + c8];
    const float4 f1 = *(const float4*)&Wfc[row*256 + c8 + 4];
    bf16x8 h, lo;
    split8(f0, f1, h, lo);
    *(bf16x8*)&Bh[row*BSTRIDE + c8] = h;
    *(bf16x8*)&Bl[row*BSTRIDE + c8] = lo;
  }
  __syncthreads();

  // persistent symmetric-C accumulators: upper pairs (a<=b)
  f32x4 accC[10];
  #pragma unroll
  for (int p=0;p<10;p++) accC[p] = (f32x4){0.f,0.f,0.f,0.f};

  unsigned short* yb = (unsigned short*)y;   // bf16 y at row*128 + 64

  for (int tile = blockIdx.x; tile < ntiles; tile += gridDim.x){
    const long r0 = (long)tile*256 + 32*wv;   // wave's 32 rows

    f32x4 accY[2][4];
    #pragma unroll
    for (int rb=0;rb<2;rb++)
      #pragma unroll
      for (int cb=0;cb<4;cb++) accY[rb][cb] = (f32x4){0.f,0.f,0.f,0.f};

    #pragma unroll 2
    for (int ks=0; ks<8; ++ks){
      const int kl = 32*ks + 8*lg;                 // lane's 8 consecutive k
      bf16x8 ahi[2];
      #pragma unroll
      for (int rb=0; rb<2; ++rb){
        const long row = r0 + 16*rb + lr;          // A row = lane&15
        float4 a0, a1;
        if (row < (long)N){
          a0 = *(const float4*)&x[row*256 + kl];
          a1 = *(const float4*)&x[row*256 + kl + 4];
        } else {
          a0 = make_float4(0.f,0.f,0.f,0.f);
          a1 = make_float4(0.f,0.f,0.f,0.f);
        }
        ahi[rb] = trunc8(a0, a1);
      }
      #pragma unroll
      for (int cb=0; cb<4; ++cb){
        const bf16x8 bhi = *(const bf16x8*)&Bh[(16*cb+lr)*BSTRIDE + kl];
        const bf16x8 blo = *(const bf16x8*)&Bl[(16*cb+lr)*BSTRIDE + kl];
        #pragma unroll
        for (int rb=0; rb<2; ++rb){
          accY[rb][cb] = MFMA16(ahi[rb], bhi, accY[rb][cb]);
          accY[rb][cb] = MFMA16(ahi[rb], blo, accY[rb][cb]);
        }
      }
    }

    // y -> global bf16 (RNE), upper 128B of each row's out-slot.
    // C/D layout (m89-verified): col = lane&15, row = 4*(lane>>4)+i
    #pragma unroll
    for (int rb=0; rb<2; ++rb){
      #pragma unroll
      for (int cb=0; cb<4; ++cb){
        #pragma unroll
        for (int i=0;i<4;i++){
          const long row = r0 + 16*rb + 4*lg + i;
          if (row < (long)N){
            const unsigned b  = __float_as_uint(accY[rb][cb][i]);
            const unsigned rn = (b + 0x7FFFu + ((b>>16)&1u)) >> 16;
            yb[row*128 + 64 + 16*cb + lr] = (unsigned short)rn;
          }
        }
      }
    }

    // in-register C contribution (K=32 = this wave's rows), full 3-product.
    // k-slot j of lane (lg,lr) := local row 16*(j>>2)+4*lg+(j&3); A and B
    // fragments share the map, MFMA k-reduction is a pure sum (r2-verified).
    bf16x8 chi[4], clo[4];
    #pragma unroll
    for (int g=0; g<4; ++g){
      const float4 u = make_float4(accY[0][g][0],accY[0][g][1],accY[0][g][2],accY[0][g][3]);
      const float4 v = make_float4(accY[1][g][0],accY[1][g][1],accY[1][g][2],accY[1][g][3]);
      split8(u, v, chi[g], clo[g]);
    }
    {
      int p = 0;
      #pragma unroll
      for (int a=0; a<4; ++a){
        #pragma unroll
        for (int b=a; b<4; ++b){
          accC[p] = MFMA16(chi[a], chi[b], accC[p]);
          accC[p] = MFMA16(clo[a], chi[b], accC[p]);
          accC[p] = MFMA16(chi[a], clo[b], accC[p]);
          ++p;
        }
      }
    }
  }

  // ---- block reduction of accC (8 waves -> 1), reusing the B LDS.
  __syncthreads();                       // B no longer needed
  float* red = (float*)SMEM;             // 4*10*256 floats = 40 KB (fits 66 KB)
  if (wv < 4){
    #pragma unroll
    for (int p=0;p<10;p++)
      *(f32x4*)&red[(wv*10+p)*256 + l*4] = accC[p];
  }
  __syncthreads();
  if (wv >= 4){
    #pragma unroll
    for (int p=0;p<10;p++){
      f32x4 v = *(f32x4*)&red[((wv-4)*10+p)*256 + l*4];
      v += accC[p];
      *(f32x4*)&red[((wv-4)*10+p)*256 + l*4] = v;
    }
  }
  __syncthreads();

  // one atomicAdd set per block: 2560 upper-triangle elements.
  for (int e = t; e < 2560; e += 512){
    const int p = e>>8, li = (e>>2)&63, i = e&3;
    const float s = red[(0*10+p)*256 + li*4 + i] + red[(1*10+p)*256 + li*4 + i]
                  + red[(2*10+p)*256 + li*4 + i] + red[(3*10+p)*256 + li*4 + i];
    const int a = (p>=4) + (p>=7) + (p>=9);
    const int off = (a==0) ? 0 : (a==1) ? 4 : (a==2) ? 7 : 9;
    const int b = a + (p - off);
    const int m = 16*a + 4*(li>>4) + i;
    const int n = 16*b + (li&15);
    atomicAdd(&C0sum[m*64 + n], s);
  }
}

#define WMAXRED(s) { s=fmaxf(s,__shfl_xor(s,32)); s=fmaxf(s,__shfl_xor(s,16)); \
  s=fmaxf(s,__shfl_xor(s,8)); s=fmaxf(s,__shfl_xor(s,4)); \
  s=fmaxf(s,__shfl_xor(s,2)); s=fmaxf(s,__shfl_xor(s,1)); }

// Coupled Newton-Schulz for C^(-1/2) via MFMA split-bf16, 512 threads.
// A=C/tau (Gershgorin tau), Y=A, Z=I; T=1.5I-0.5ZY; Y<-YT; Z<-TZ; W=Z/sqrt(tau).
// Per iter: T-step (8 waves: row-block w>>1, 2 col-blocks each), barrier,
// DUAL step (waves 0-3: U=Y*T; waves 4-7: V=T*Z), barrier; rotate 5 buffers.
// C0sum is block-upper-triangular (16x16 tiles): symmetrize on load.
__global__ __launch_bounds__(512,1) void k_whiten_ns(const float* __restrict__ C0sum,
                                                     unsigned short* __restrict__ Wh2,
                                                     unsigned short* __restrict__ Wl2,
                                                     float invN){
  __shared__ __align__(16) unsigned short SM[10][64*WST]; // Y,Z,T,U,V (hi,lo each)
  __shared__ float sred[8];

  const int t = threadIdx.x;
  const int w = t>>6, l = t&63;
  const int lg = l>>4, lr = l&15;
  const int di = t>>3, djb = (t&7)*8;     // thread: row di, cols [djb, djb+8)

  // ---- load C (symmetrize), Gershgorin tau
  const bool upper = (((t&7)>>1) >= (di>>4));   // col-tile >= row-tile
  float4 cv[2];
  float psum = 0.f;
  #pragma unroll
  for (int c=0;c<2;c++){
    if (upper){
      cv[c] = *(const float4*)&C0sum[di*64 + djb + 4*c];
    } else {
      const int j0 = djb + 4*c;
      cv[c] = make_float4(C0sum[(j0+0)*64 + di], C0sum[(j0+1)*64 + di],
                          C0sum[(j0+2)*64 + di], C0sum[(j0+3)*64 + di]);
    }
    psum += fabsf(cv[c].x)+fabsf(cv[c].y)+fabsf(cv[c].z)+fabsf(cv[c].w);
  }
  psum *= invN;
  psum += __shfl_xor(psum,1);
  psum += __shfl_xor(psum,2);
  psum += __shfl_xor(psum,4);
  float m = psum;
  WMAXRED(m);
  if (l==0) sred[w] = m;
  __syncthreads();
  float tau = sred[0];
  #pragma unroll
  for (int i=1;i<8;i++) tau = fmaxf(tau, sred[i]);
  const float sA = invN/tau;

  // ---- init Y = A (split), Z = I (split)
  #pragma unroll
  for (int c=0;c<2;c++){
    const float vv[4] = {cv[c].x*sA, cv[c].y*sA, cv[c].z*sA, cv[c].w*sA};
    #pragma unroll
    for (int e=0;e<4;e++){
      const int j = djb + 4*c + e;
      const unsigned b  = __float_as_uint(vv[e]);
      const unsigned hb = b & 0xFFFF0000u;
      SM[0][di*WST + j] = (unsigned short)(hb >> 16);
      SM[1][di*WST + j] =
          (unsigned short)(__float_as_uint(vv[e] - __uint_as_float(hb)) >> 16);
      SM[2][di*WST + j] = (di==j) ? (unsigned short)0x3F80 : (unsigned short)0;
      SM[3][di*WST + j] = 0;
    }
  }
  __syncthreads();

  unsigned short *pYh=SM[0], *pYl=SM[1], *pZh=SM[2], *pZl=SM[3];
  unsigned short *pTh=SM[4], *pTl=SM[5], *pUh=SM[6], *pUl=SM[7];
  unsigned short *pVh=SM[8], *pVl=SM[9];

  // pack+store one 16x16 D tile transposed (D symmetric): val at (row,col)
  // stored at [col][row]; row = 16*rw+4*lg+i, col = 16*cb+lr.
  auto storeT = [&](unsigned short* Dh, unsigned short* Dl,
                    const f32x4& a, int rw, int cb, bool isT){
    unsigned hh[4], ll[4];
    #pragma unroll
    for (int i=0;i<4;i++){
      float v = a[i];
      if (isT) v = -0.5f*v + ((16*rw+4*lg+i == 16*cb+lr) ? 1.5f : 0.f);
      const unsigned b  = __float_as_uint(v);
      const unsigned hb = b & 0xFFFF0000u;
      hh[i] = hb >> 16;
      ll[i] = __float_as_uint(v - __uint_as_float(hb)) >> 16;
    }
    const int base = (16*cb+lr)*WST + 16*rw + 4*lg;
    *(uint2*)&Dh[base] = make_uint2(hh[0] | (hh[1]<<16), hh[2] | (hh[3]<<16));
    *(uint2*)&Dl[base] = make_uint2(ll[0] | (ll[1]<<16), ll[2] | (ll[3]<<16));
  };

  // T-step: this wave computes rows [16*rw,16*rw+16), cols 2 blocks from cb0.
  auto mm2 = [&](unsigned short* Dh, unsigned short* Dl,
                 const unsigned short* Ah, const unsigned short* Al,
                 const unsigned short* Bh, const unsigned short* Bl,
                 int rw, int cb0){
    f32x4 acc[2];
    acc[0] = (f32x4){0.f,0.f,0.f,0.f};
    acc[1] = (f32x4){0.f,0.f,0.f,0.f};
    #pragma unroll
    for (int ks=0; ks<2; ++ks){
      const int kl = 32*ks + 8*lg;
      const bf16x8 ahi = *(const bf16x8*)&Ah[(16*rw+lr)*WST + kl];
      const bf16x8 alo = *(const bf16x8*)&Al[(16*rw+lr)*WST + kl];
      #pragma unroll
      for (int cbi=0; cbi<2; ++cbi){
        const bf16x8 bhi = *(const bf16x8*)&Bh[(16*(cb0+cbi)+lr)*WST + kl];
        const bf16x8 blo = *(const bf16x8*)&Bl[(16*(cb0+cbi)+lr)*WST + kl];
        acc[cbi] = MFMA16(ahi, bhi, acc[cbi]);
        acc[cbi] = MFMA16(alo, bhi, acc[cbi]);
        acc[cbi] = MFMA16(ahi, blo, acc[cbi]);
      }
    }
    storeT(Dh, Dl, acc[0], rw, cb0+0, true);
    storeT(Dh, Dl, acc[1], rw, cb0+1, true);
  };

  // dual-step: full-width mm, this wave computes rows [16*rw,16*rw+16), 4 cbs.
  auto mm4 = [&](unsigned short* Dh, unsigned short* Dl,
                 const unsigned short* Ah, const unsigned short* Al,
                 const unsigned short* Bh, const unsigned short* Bl, int rw){
    f32x4 acc[4];
    #pragma unroll
    for (int cb=0;cb<4;cb++) acc[cb] = (f32x4){0.f,0.f,0.f,0.f};
    #pragma unroll
    for (int ks=0; ks<2; ++ks){
      const int kl = 32*ks + 8*lg;
      const bf16x8 ahi = *(const bf16x8*)&Ah[(16*rw+lr)*WST + kl];
      const bf16x8 alo = *(const bf16x8*)&Al[(16*rw+lr)*WST + kl];
      #pragma unroll
      for (int cb=0; cb<4; ++cb){
        const bf16x8 bhi = *(const bf16x8*)&Bh[(16*cb+lr)*WST + kl];
        const bf16x8 blo = *(const bf16x8*)&Bl[(16*cb+lr)*WST + kl];
        acc[cb] = MFMA16(ahi, bhi, acc[cb]);
        acc[cb] = MFMA16(alo, bhi, acc[cb]);
        acc[cb] = MFMA16(ahi, blo, acc[cb]);
      }
    }
    #pragma unroll
    for (int cb=0;cb<4;cb++) storeT(Dh, Dl, acc[cb], rw, cb, false);
  };

  #pragma unroll 1
  for (int it=0; it<NS_ITERS; ++it){
    // T = 1.5I - 0.5 Z Y : all 8 waves (row-block w>>1, col-blocks 2*(w&1)+)
    mm2(pTh,pTl, pZh,pZl, pYh,pYl, w>>1, 2*(w&1));
    __syncthreads();
    // dual: waves 0-3: U = Y*T (new Y, skip on last); waves 4-7: V = T*Z (new Z)
    if (w < 4){
      if (it < NS_ITERS-1) mm4(pUh,pUl, pYh,pYl, pTh,pTl, w);
    } else {
      mm4(pVh,pVl, pTh,pTl, pZh,pZl, w-4);
    }
    __syncthreads();
    unsigned short *oYh=pYh,*oYl=pYl,*oZh=pZh,*oZl=pZl,*oTh=pTh,*oTl=pTl;
    pYh=pUh; pYl=pUl; pZh=pVh; pZl=pVl;
    pTh=oYh; pTl=oYl; pUh=oZh; pUl=oZl; pVh=oTh; pVl=oTl;
  }

  // ---- W = Z / sqrt(tau): reconstruct, scale, re-split, store global
  const float fs = rsqrtf(tau);
  #pragma unroll
  for (int c=0;c<2;c++){
    #pragma unroll
    for (int e=0;e<4;e++){
      const int j = djb + 4*c + e;
      const float zh = __uint_as_float(((unsigned)pZh[di*WST + j]) << 16);
      const float zl = __uint_as_float(((unsigned)pZl[di*WST + j]) << 16);
      const float v  = (zh + zl) * fs;
      const unsigned b  = __float_as_uint(v);
      const unsigned hb = b & 0xFFFF0000u;
      Wh2[di*64 + j] = (unsigned short)(hb >> 16);
      Wl2[di*64 + j] =
          (unsigned short)(__float_as_uint(v - __uint_as_float(hb)) >> 16);
    }
  }
}

// In-place MFMA: out[row] = y_bf16[row] @ W. y bf16 lives in the upper 128B
// of each row's 256B out-slot; W symmetric split-bf16 (16KB, L1-resident).
// Wave wv owns rows [32wv,32wv+32) exclusively (reads its rows' bf16, then
// overwrites the same rows' f32 -- within-wave program order, race-free).
// (256,6): no LDS, ~63 live VGPR < 84 cap -> 6 blocks/CU for latency hiding.
__global__ __launch_bounds__(256,6) void k_yw(float* yio,
                                              const unsigned short* __restrict__ Wh2,
                                              const unsigned short* __restrict__ Wl2,
                                              int N){
  const int t  = threadIdx.x;
  const int wv = t>>6, l = t&63;
  const int lg = l>>4, lr = l&15;
  const long r0 = (long)blockIdx.x*128;
  const unsigned short* yb = (const unsigned short*)yio;

  f32x4 acc[2][4];
  #pragma unroll
  for (int rb=0;rb<2;rb++)
    #pragma unroll
    for (int cb=0;cb<4;cb++) acc[rb][cb] = (f32x4){0.f,0.f,0.f,0.f};

  #pragma unroll
  for (int ks=0; ks<2; ++ks){
    const int kl = 32*ks + 8*lg;
    bf16x8 ahi[2];
    #pragma unroll
    for (int rb=0; rb<2; ++rb){
      const long row = r0 + 32*wv + 16*rb + lr;
      if (row < (long)N)
        ahi[rb] = *(const bf16x8*)&yb[row*128 + 64 + kl];
      else
        ahi[rb] = (bf16x8){0,0,0,0,0,0,0,0};
    }
    #pragma unroll
    for (int cb=0; cb<4; ++cb){
      const bf16x8 bhi = *(const bf16x8*)&Wh2[(16*cb+lr)*64 + kl];
      const bf16x8 blo = *(const bf16x8*)&Wl2[(16*cb+lr)*64 + kl];
      #pragma unroll
      for (int rb=0; rb<2; ++rb){
        acc[rb][cb] = MFMA16(ahi[rb], bhi, acc[rb][cb]);
        acc[rb][cb] = MFMA16(ahi[rb], blo, acc[rb][cb]);
      }
    }
  }

  #pragma unroll
  for (int rb=0; rb<2; ++rb){
    #pragma unroll
    for (int cb=0; cb<4; ++cb){
      #pragma unroll
      for (int i=0;i<4;i++){
        const long row = r0 + 32*wv + 16*rb + 4*lg + i;
        if (row < (long)N) yio[row*64 + 16*cb + lr] = acc[rb][cb][i];
      }
    }
  }
}

extern "C" void kernel_launch(void* const* d_in, const int* in_sizes, int n_in,
                              void* d_out, int out_size, void* d_ws, size_t ws_size,
                              hipStream_t stream) {
  const float* x   = (const float*)d_in[0];   // [N,256]
  const float* Wfc = (const float*)d_in[1];   // [64,256]
  const float* R   = (const float*)d_in[2];   // unused: W = C^-1/2 exactly
  float* out = (float*)d_out;                 // [N,64] (holds y bf16, then out)
  char*  ws  = (char*)d_ws;
  (void)R;

  float*          C0sum = (float*)(ws + 0);               // 16 KB
  unsigned short* Wh2   = (unsigned short*)(ws + 16384);  //  8 KB (split W)
  unsigned short* Wl2   = (unsigned short*)(ws + 24576);  //  8 KB

  const int N = in_sizes[0] / 256;
  const int nt128 = (N + 127)/128;
  const int nt256 = (N + 255)/256;

  hipMemsetAsync(C0sum, 0, 16384, stream);
  k_pass     <<<512,   512, 0, stream>>>(x, Wfc, out, C0sum, N, nt256);
  k_whiten_ns<<<1,     512, 0, stream>>>(C0sum, Wh2, Wl2, 1.0f/(float)N);
  k_yw       <<<nt128, 256, 0, stream>>>(out, Wh2, Wl2, N);
}